// Round 11
// baseline (661.875 us; speedup 1.0000x reference)
//
#include <hip/hip_runtime.h>
#include <hip/hip_bf16.h>

typedef unsigned short u16;
typedef __attribute__((ext_vector_type(4))) float f32x4;
typedef __attribute__((ext_vector_type(16))) float f32x16;
typedef __attribute__((ext_vector_type(8))) short bf16x8;
typedef __attribute__((ext_vector_type(4))) int i32x4;
typedef __attribute__((ext_vector_type(4))) unsigned short u16x4;

#define DEVI static __device__ __forceinline__

DEVI u16 f2bf(float f) {
  __hip_bfloat16 h = __float2bfloat16(f);
  return *reinterpret_cast<u16*>(&h);
}
DEVI float bf2f(u16 u) {
  unsigned int x = ((unsigned int)u) << 16;
  return __uint_as_float(x);
}
DEVI float exp2a(float x) {
  float r;
  asm("v_exp_f32 %0, %1" : "=v"(r) : "v"(x));
  return r;
}
DEVI int cvtpk(float lo, float hi) {
  int r;
  asm("v_cvt_pk_bf16_f32 %0, %1, %2" : "=v"(r) : "v"(lo), "v"(hi));
  return r;
}
DEVI f32x16 mfma32(bf16x8 a, bf16x8 b, f32x16 c) {
  return __builtin_amdgcn_mfma_f32_32x32x16_bf16(a, b, c, 0, 0, 0);
}
DEVI float xhalf_sum(float x) {
  float a = x, b;
  asm volatile("v_mov_b32 %0, %1" : "=v"(b) : "v"(x));
  asm volatile("v_permlane32_swap_b32 %0, %1" : "+v"(a), "+v"(b));
  return a + b;
}

DEVI void gload_lds16(const void* g, void* l) {
  __builtin_amdgcn_global_load_lds(
      (const __attribute__((address_space(1))) unsigned int*)g,
      (__attribute__((address_space(3))) unsigned int*)l, 16, 0, 0);
}

#define BAR() __builtin_amdgcn_s_barrier()
#define WAITV0() asm volatile("s_waitcnt vmcnt(0)" ::: "memory")
#define WAITV4() asm volatile("s_waitcnt vmcnt(4)" ::: "memory")

// ---------------- fused f32 -> bf16 conversion (X, Y, 4 weights) ----------------
__global__ __launch_bounds__(256) void k_convall(
    const float* __restrict__ X, const float* __restrict__ Y,
    const float* __restrict__ Wq, const float* __restrict__ Wk,
    const float* __restrict__ Wv, const float* __restrict__ Wo,
    u16* __restrict__ Xb, u16* __restrict__ Yb, u16* __restrict__ Wb) {
  long i = ((long)blockIdx.x * 256 + threadIdx.x) * 8;
  const float* s;
  u16* d;
  long off;
  if (i < 4194304) {
    s = X; d = Xb; off = i;
  } else if (i < 8388608) {
    s = Y; d = Yb; off = i - 4194304;
  } else {
    long w = (i - 8388608) >> 18;
    off = (i - 8388608) & 262143;
    s = w == 0 ? Wq : w == 1 ? Wk : w == 2 ? Wv : Wo;
    d = Wb + w * 262144;
  }
  f32x4 a = *(const f32x4*)(s + off);
  f32x4 b = *(const f32x4*)(s + off + 4);
  bf16x8 v;
#pragma unroll
  for (int j = 0; j < 4; ++j) {
    v[j]     = (short)f2bf(a[j]);
    v[4 + j] = (short)f2bf(b[j]);
  }
  *(bf16x8*)(d + off) = v;
}

// ---------------- GEMM core: BM=128 BN=64 BK=64, 4 waves, 2-phase prefetch ------
struct GemmAcc { f32x4 acc[4][2]; };

DEVI void gemm_body(const u16* __restrict__ A, const u16* __restrict__ Bw,
                    int m0, int n0, char* sm, GemmAcc& G) {
  const int tid = threadIdx.x;
  const int wid = tid >> 6, lane = tid & 63;
  const int g = lane >> 4, li = lane & 15;
  const int wr = wid >> 1, wc = wid & 1;

  int arow[4], acol[4];
#pragma unroll
  for (int i = 0; i < 4; ++i) {
    int P0 = ((i * 4 + wid) << 10) + lane * 16;
    int L0 = P0 ^ (((P0 >> 7) & 7) << 4);
    arow[i] = L0 >> 7;
    acol[i] = L0 & 127;
  }

#pragma unroll
  for (int mr = 0; mr < 4; ++mr)
#pragma unroll
    for (int nr = 0; nr < 2; ++nr) G.acc[mr][nr] = (f32x4){0.f, 0.f, 0.f, 0.f};

  auto stage = [&](int kt, int half) {
    char* As = sm + half * 24576;
    char* Bs = As + 16384;
    const int k0b = kt * 128;
#pragma unroll
    for (int i = 0; i < 4; ++i)
      gload_lds16((const char*)A + (size_t)(m0 + arow[i]) * 1024 + k0b + acol[i],
                  As + ((i * 4 + wid) << 10));
#pragma unroll
    for (int i = 0; i < 2; ++i)
      gload_lds16((const char*)Bw + (size_t)(n0 + arow[i]) * 1024 + k0b + acol[i],
                  Bs + ((i * 4 + wid) << 10));
  };

  stage(0, 0);
#pragma unroll 1
  for (int kt = 0; kt < 8; ++kt) {
    const int half = kt & 1;
    if (kt < 7) {
      stage(kt + 1, half ^ 1);
      asm volatile("s_waitcnt vmcnt(6)" ::: "memory");
    } else {
      asm volatile("s_waitcnt vmcnt(0)" ::: "memory");
    }
    BAR();
    const char* As = sm + half * 24576;
    const char* Bs = As + 16384;
#pragma unroll
    for (int ks = 0; ks < 2; ++ks) {
      bf16x8 af[4], bfr[2];
#pragma unroll
      for (int mr = 0; mr < 4; ++mr) {
        int row = wr * 64 + mr * 16 + li;
        int L = row * 128 + ks * 64 + g * 16;
        int P = L ^ ((row & 7) << 4);
        af[mr] = *(const bf16x8*)(As + P);
      }
#pragma unroll
      for (int nr = 0; nr < 2; ++nr) {
        int row = wc * 32 + nr * 16 + li;
        int L = row * 128 + ks * 64 + g * 16;
        int P = L ^ ((row & 7) << 4);
        bfr[nr] = *(const bf16x8*)(Bs + P);
      }
#pragma unroll
      for (int mr = 0; mr < 4; ++mr)
#pragma unroll
        for (int nr = 0; nr < 2; ++nr)
          G.acc[mr][nr] = __builtin_amdgcn_mfma_f32_16x16x32_bf16(
              af[mr], bfr[nr], G.acc[mr][nr], 0, 0, 0);
    }
    BAR();
  }
}

// Fused QKV: z=0 -> Q [B][H][N][64], z=1 -> K same,
// z=2 -> V^T DIRECT: C = Wv @ Y^T -> coalesced [B][H][64][N] writes.
__global__ __launch_bounds__(256) void k_gemm_qkv(
    const u16* __restrict__ Xb, const u16* __restrict__ Yb,
    const u16* __restrict__ Wall, const float* __restrict__ bq,
    const float* __restrict__ bk, const float* __restrict__ bv,
    u16* __restrict__ Qb, u16* __restrict__ Kb, u16* __restrict__ Vtb) {
  __shared__ __align__(16) char sm[49152];
  const int z = blockIdx.z;
  int lin = blockIdx.x + 8 * blockIdx.y;
  int xcd = lin & 7, slot = lin >> 3;

  const u16 *Ag, *Bg;
  int m0, n0;
  if (z == 2) {
    Ag = Wall + 2 * 262144;  // Wv
    Bg = Yb;
    m0 = (slot >> 4) * 128;
    n0 = (xcd * 16 + (slot & 15)) * 64;
  } else {
    Ag = z ? Yb : Xb;
    Bg = Wall + (size_t)z * 262144;
    m0 = (xcd * 8 + (slot >> 3)) * 128;
    n0 = (slot & 7) * 64;
  }

  GemmAcc G;
  gemm_body(Ag, Bg, m0, n0, sm, G);

  const int tid = threadIdx.x;
  const int wid = tid >> 6, lane = tid & 63;
  const int g = lane >> 4, li = lane & 15;
  const int wr = wid >> 1, wc = wid & 1;

  if (z <= 1) {
    u16* Cout = z ? Kb : Qb;
    const float* bias = z ? bk : bq;
#pragma unroll
    for (int nr = 0; nr < 2; ++nr) {
      int col = n0 + wc * 32 + nr * 16 + li;
      float bvv = bias[col];
#pragma unroll
      for (int mr = 0; mr < 4; ++mr) {
#pragma unroll
        for (int j = 0; j < 4; ++j) {
          int row = m0 + wr * 64 + mr * 16 + g * 4 + j;
          float v = G.acc[mr][nr][j] + bvv;
          int b = row >> 11, nn = row & 2047, h = col >> 6, dd = col & 63;
          Cout[(((size_t)(b * 8 + h) << 11) + nn) * 64 + dd] = f2bf(v);
        }
      }
    }
  } else {
#pragma unroll
    for (int mr = 0; mr < 4; ++mr) {
#pragma unroll
      for (int j = 0; j < 4; ++j) {
        int row = m0 + wr * 64 + mr * 16 + g * 4 + j;
        float bvv = bv[row];
        int hh = row >> 6, dd = row & 63;
#pragma unroll
        for (int nr = 0; nr < 2; ++nr) {
          int col = n0 + wc * 32 + nr * 16 + li;
          int b = col >> 11, nn = col & 2047;
          Vtb[(((size_t)(b * 8 + hh) * 64) + dd) * 2048 + nn] =
              f2bf(G.acc[mr][nr][j] + bvv);
        }
      }
    }
  }
}

// Final projection: f32 row-major output [M][512]
__global__ __launch_bounds__(256) void k_gemm_out(const u16* __restrict__ A,
                                                  const u16* __restrict__ Bw,
                                                  const float* __restrict__ bias,
                                                  float* __restrict__ Cout) {
  __shared__ __align__(16) char sm[49152];
  int lin = blockIdx.x + 8 * blockIdx.y;
  int xcd = lin & 7, slot = lin >> 3;
  int by = xcd * 8 + (slot >> 3), bx = slot & 7;
  const int m0 = by * 128, n0 = bx * 64;

  GemmAcc G;
  gemm_body(A, Bw, m0, n0, sm, G);

  const int tid = threadIdx.x;
  const int wid = tid >> 6, lane = tid & 63;
  const int g = lane >> 4, li = lane & 15;
  const int wr = wid >> 1, wc = wid & 1;
#pragma unroll
  for (int nr = 0; nr < 2; ++nr) {
    int col = n0 + wc * 32 + nr * 16 + li;
    float bvv = bias[col];
#pragma unroll
    for (int mr = 0; mr < 4; ++mr) {
#pragma unroll
      for (int j = 0; j < 4; ++j) {
        int row = m0 + wr * 64 + mr * 16 + g * 4 + j;
        Cout[(size_t)row * 512 + col] = G.acc[mr][nr][j] + bvv;
      }
    }
  }
}

// ---------------- flash attention: q=64/wave, kv-split-4, 16 waves, LDS-staged V ----
// Q,K: [B*H][2048][64] bf16; Vt: [B*H][64][2048] bf16; Ob: [B][2048][512] bf16
// 256 blocks (32 bh x 8 qtiles of 256 rows); 16 waves = 4 KV groups x 4 q-waves.
// Group g owns kv quarter (8 tiles of 64); ring (32KB): buf{0,1} x {K 8K, V 8K}.
// launch_bounds(1024,2): VGPR cap 256, kernel needs ~124 -> no spill, 4 waves/SIMD.
DEVI void attn_phase(const char* L, int kb, int vb, const int* v4, int sv0, int sv1,
                     const bf16x8* qfA, const bf16x8* qfB,
                     f32x16& oA0, f32x16& oA1, f32x16& oB0, f32x16& oB1,
                     float& lsumA, float& lsumB) {
  const f32x16 Z = {};
  f32x16 sA, sB;
  bf16x8 kf;
  kf = *(const bf16x8*)(L + kb + v4[0]);
  sA = mfma32(kf, qfA[0], Z);  sB = mfma32(kf, qfB[0], Z);
  kf = *(const bf16x8*)(L + kb + v4[1]);
  sA = mfma32(kf, qfA[1], sA); sB = mfma32(kf, qfB[1], sB);
  kf = *(const bf16x8*)(L + kb + v4[2]);
  sA = mfma32(kf, qfA[2], sA); sB = mfma32(kf, qfB[2], sB);
  kf = *(const bf16x8*)(L + kb + v4[3]);
  sA = mfma32(kf, qfA[3], sA); sB = mfma32(kf, qfB[3], sB);

  // V reads issued early: latency hides under the exp block
  bf16x8 va0l = *(const bf16x8*)(L + vb + v4[sv0]);
  bf16x8 va0h = *(const bf16x8*)(L + vb + 4096 + v4[sv0]);
  bf16x8 va1l = *(const bf16x8*)(L + vb + v4[sv1]);
  bf16x8 va1h = *(const bf16x8*)(L + vb + 4096 + v4[sv1]);

  // P = 2^S (Q pre-scaled); row-sums
#pragma unroll
  for (int i = 0; i < 16; ++i) sA[i] = exp2a(sA[i]);
#pragma unroll
  for (int i = 0; i < 16; ++i) sB[i] = exp2a(sB[i]);
  float tA[4], tB[4];
#pragma unroll
  for (int i = 0; i < 4; ++i) {
    tA[i] = (sA[4 * i] + sA[4 * i + 1]) + (sA[4 * i + 2] + sA[4 * i + 3]);
    tB[i] = (sB[4 * i] + sB[4 * i + 1]) + (sB[4 * i + 2] + sB[4 * i + 3]);
  }
  lsumA += (tA[0] + tA[1]) + (tA[2] + tA[3]);
  lsumB += (tB[0] + tB[1]) + (tB[2] + tB[3]);

  // pack P slices: kt=0 -> kv slice sv0, kt=1 -> kv slice sv1
  bf16x8 pbA[2], pbB[2];
#pragma unroll
  for (int kt = 0; kt < 2; ++kt) {
    const int base = kt * 8;
    int a0 = cvtpk(sA[base + 0], sA[base + 1]);
    int a1 = cvtpk(sA[base + 2], sA[base + 3]);
    int b0 = cvtpk(sA[base + 4], sA[base + 5]);
    int b1 = cvtpk(sA[base + 6], sA[base + 7]);
    asm volatile("v_permlane32_swap_b32 %0, %1" : "+v"(a0), "+v"(b0));
    asm volatile("v_permlane32_swap_b32 %0, %1" : "+v"(a1), "+v"(b1));
    i32x4 pi = {a0, a1, b0, b1};
    pbA[kt] = __builtin_bit_cast(bf16x8, pi);
    int c0 = cvtpk(sB[base + 0], sB[base + 1]);
    int c1 = cvtpk(sB[base + 2], sB[base + 3]);
    int d0 = cvtpk(sB[base + 4], sB[base + 5]);
    int d1 = cvtpk(sB[base + 6], sB[base + 7]);
    asm volatile("v_permlane32_swap_b32 %0, %1" : "+v"(c0), "+v"(d0));
    asm volatile("v_permlane32_swap_b32 %0, %1" : "+v"(c1), "+v"(d1));
    i32x4 qi = {c0, c1, d0, d1};
    pbB[kt] = __builtin_bit_cast(bf16x8, qi);
  }

  // PV: each va feeds both q-halves
  oA0 = mfma32(va0l, pbA[0], oA0);
  oB0 = mfma32(va0l, pbB[0], oB0);
  oA1 = mfma32(va0h, pbA[0], oA1);
  oB1 = mfma32(va0h, pbB[0], oB1);
  oA0 = mfma32(va1l, pbA[1], oA0);
  oB0 = mfma32(va1l, pbB[1], oB0);
  oA1 = mfma32(va1h, pbA[1], oA1);
  oB1 = mfma32(va1h, pbB[1], oB1);
}

__global__ __launch_bounds__(1024, 2) void k_attn(const u16* __restrict__ Qb,
                                                  const u16* __restrict__ Kb,
                                                  const u16* __restrict__ Vt,
                                                  u16* __restrict__ Ob) {
  __shared__ __align__(16) char lds[131072];  // 4 groups x 32KB rings; merge reuses
  const int tid = threadIdx.x, wid = tid >> 6, lane = tid & 63;
  const int li = lane & 31, h = lane >> 5;
  const int grp = wid >> 2, w4 = wid & 3;

  const int lin = blockIdx.x;
  const int xcd = lin & 7, slot = lin >> 3;       // slot 0..31
  const int bh = xcd * 4 + (slot >> 3);
  const int qt = slot & 7;                        // 8 q-tiles of 256 rows
  const int start = (slot * 3) & 7;

  const u16* Qh = Qb + ((size_t)bh << 11) * 64;
  const char* Khb = (const char*)(Kb + ((size_t)bh << 11) * 64);
  const char* Vhb = (const char*)(Vt + (size_t)bh * 64 * 2048);

  int v4[4];
  {
    const int swz = (li & 7) << 4;
#pragma unroll
    for (int s = 0; s < 4; ++s) v4[s] = li * 128 + ((s * 32 + h * 16) ^ swz);
  }

  const int qA = qt * 256 + w4 * 64 + li;
  const int qB = qA + 32;
  const float C2 = 0.18033688f;  // 0.125 * log2(e)
  bf16x8 qfA[4], qfB[4];
#pragma unroll
  for (int k4 = 0; k4 < 4; ++k4) {
    bf16x8 fA = *(const bf16x8*)(Qh + (size_t)qA * 64 + k4 * 16 + h * 8);
    bf16x8 fB = *(const bf16x8*)(Qh + (size_t)qB * 64 + k4 * 16 + h * 8);
    bf16x8 rA, rB;
#pragma unroll
    for (int e = 0; e < 4; ++e) {
      int pA = cvtpk(bf2f((u16)fA[2 * e]) * C2, bf2f((u16)fA[2 * e + 1]) * C2);
      rA[2 * e]     = (short)(pA & 0xffff);
      rA[2 * e + 1] = (short)((unsigned)pA >> 16);
      int pB = cvtpk(bf2f((u16)fB[2 * e]) * C2, bf2f((u16)fB[2 * e + 1]) * C2);
      rB[2 * e]     = (short)(pB & 0xffff);
      rB[2 * e + 1] = (short)((unsigned)pB >> 16);
    }
    qfA[k4] = rA;
    qfB[k4] = rB;
  }

  // staging: group's 4 waves cover K tile (8KB) + V tile (8KB); 2KB each per wave
  char* gb = lds + grp * 32768;
  const char* Lg = gb;
  int ksrc[2], vsrc[2];
#pragma unroll
  for (int j = 0; j < 2; ++j) {
    int P0 = w4 * 2048 + j * 1024 + lane * 16;
    int L0 = P0 ^ (((P0 >> 7) & 7) << 4);
    ksrc[j] = L0;
    vsrc[j] = (L0 >> 7) * 4096 + (L0 & 127);
  }

  auto T = [&](int n) { return grp * 8 + ((start + n) & 7); };
  auto stage = [&](int tt, int bb) {
#pragma unroll
    for (int j = 0; j < 2; ++j)
      gload_lds16(Khb + (size_t)tt * 8192 + ksrc[j],
                  gb + bb + w4 * 2048 + j * 1024);
#pragma unroll
    for (int j = 0; j < 2; ++j)
      gload_lds16(Vhb + (size_t)tt * 128 + vsrc[j],
                  gb + bb + 8192 + w4 * 2048 + j * 1024);
  };

  f32x16 oA0 = {}, oA1 = {}, oB0 = {}, oB1 = {};
  float lsumA = 0.f, lsumB = 0.f;

  stage(T(0), 0);
  stage(T(1), 16384);
  WAITV4();  // tile 0 landed
  BAR();

#pragma unroll 1
  for (int it = 0; it < 6; ++it) {
    const int cur = (it & 1) * 16384;
    attn_phase(Lg, cur, cur + 8192, v4, 0, 1, qfA, qfB, oA0, oA1, oB0, oB1,
               lsumA, lsumB);
    attn_phase(Lg, cur + 4096, cur + 8192, v4, 2, 3, qfA, qfB, oA0, oA1, oB0, oB1,
               lsumA, lsumB);
    BAR();
    stage(T(it + 2), cur);
    WAITV4();
    BAR();
  }
  // tile 6
  attn_phase(Lg, 0, 8192, v4, 0, 1, qfA, qfB, oA0, oA1, oB0, oB1, lsumA, lsumB);
  attn_phase(Lg, 4096, 8192, v4, 2, 3, qfA, qfB, oA0, oA1, oB0, oB1, lsumA, lsumB);
  WAITV0();
  BAR();
  // tile 7
  attn_phase(Lg, 16384, 24576, v4, 0, 1, qfA, qfB, oA0, oA1, oB0, oB1, lsumA, lsumB);
  attn_phase(Lg, 20480, 24576, v4, 2, 3, qfA, qfB, oA0, oA1, oB0, oB1, lsumA, lsumB);

  // ---- merge the 4 KV quarters through LDS (common implicit max -> plain adds) ----
  __syncthreads();
  if (grp == 1 || grp == 2) {
    char* dst = lds + (grp - 1) * 65536 + w4 * 16384;
#pragma unroll
    for (int j = 0; j < 16; ++j) {
      const f32x16& o = (j < 4) ? oA0 : (j < 8) ? oA1 : (j < 12) ? oB0 : oB1;
      const int s2 = (j & 3) * 4;
      f32x4 c = {o[s2 + 0], o[s2 + 1], o[s2 + 2], o[s2 + 3]};
      *(f32x4*)(dst + j * 1024 + lane * 16) = c;
    }
  }
  __syncthreads();
  if (grp == 0) {
#pragma unroll
    for (int half = 0; half < 2; ++half) {
      const char* src = lds + half * 65536 + w4 * 16384;
#pragma unroll
      for (int j = 0; j < 16; ++j) {
        f32x4 c = *(const f32x4*)(src + j * 1024 + lane * 16);
        f32x16& o = (j < 4) ? oA0 : (j < 8) ? oA1 : (j < 12) ? oB0 : oB1;
        const int s2 = (j & 3) * 4;
        o[s2 + 0] += c[0]; o[s2 + 1] += c[1]; o[s2 + 2] += c[2]; o[s2 + 3] += c[3];
      }
    }
  }
  __syncthreads();
  if (grp == 3) {
    char* dst = lds + w4 * 16384;
#pragma unroll
    for (int j = 0; j < 16; ++j) {
      const f32x16& o = (j < 4) ? oA0 : (j < 8) ? oA1 : (j < 12) ? oB0 : oB1;
      const int s2 = (j & 3) * 4;
      f32x4 c = {o[s2 + 0], o[s2 + 1], o[s2 + 2], o[s2 + 3]};
      *(f32x4*)(dst + j * 1024 + lane * 16) = c;
    }
  }
  __syncthreads();
  if (grp == 0) {
    const char* src = lds + w4 * 16384;
#pragma unroll
    for (int j = 0; j < 16; ++j) {
      f32x4 c = *(const f32x4*)(src + j * 1024 + lane * 16);
      f32x16& o = (j < 4) ? oA0 : (j < 8) ? oA1 : (j < 12) ? oB0 : oB1;
      const int s2 = (j & 3) * 4;
      o[s2 + 0] += c[0]; o[s2 + 1] += c[1]; o[s2 + 2] += c[2]; o[s2 + 3] += c[3];
    }
  }
  __syncthreads();
  if (grp != 0) {
    float* dst = (float*)(lds + (grp - 1) * 2048) + w4 * 128 + lane * 2;
    dst[0] = lsumA;
    dst[1] = lsumB;
  }
  __syncthreads();
  if (grp == 0) {
#pragma unroll
    for (int g2 = 1; g2 < 4; ++g2) {
      const float* src = (const float*)(lds + (g2 - 1) * 2048) + w4 * 128 + lane * 2;
      lsumA += src[0];
      lsumB += src[1];
    }
    const float invA = 1.0f / xhalf_sum(lsumA);
    const float invB = 1.0f / xhalf_sum(lsumB);

    const int b = bh >> 3, head = bh & 7;
#pragma unroll
    for (int half = 0; half < 2; ++half) {
      const int q = half ? qB : qA;
      const float inv = half ? invB : invA;
      u16* orow = Ob + ((size_t)(b * 2048 + q)) * 512 + head * 64;
      const u16* qrow = Qh + (size_t)q * 64;
#pragma unroll
      for (int dt = 0; dt < 2; ++dt) {
        const f32x16& o = half ? (dt ? oB1 : oB0) : (dt ? oA1 : oA0);
#pragma unroll
        for (int s2 = 0; s2 < 4; ++s2) {
          int d0 = dt * 32 + s2 * 8 + h * 4;
          u16x4 qv = *(const u16x4*)(qrow + d0);
          u16x4 w;
#pragma unroll
          for (int j = 0; j < 4; ++j)
            w[j] = f2bf(fmaf(o[s2 * 4 + j], inv, bf2f(qv[j])));
          *(u16x4*)(orow + d0) = w;
        }
      }
    }
  }
}

// ---------------- launch ----------------
extern "C" void kernel_launch(void* const* d_in, const int* in_sizes, int n_in,
                              void* d_out, int out_size, void* d_ws, size_t ws_size,
                              hipStream_t stream) {
  const float* X  = (const float*)d_in[0];
  const float* Y  = (const float*)d_in[1];
  const float* Wq = (const float*)d_in[2];
  const float* bq = (const float*)d_in[3];
  const float* Wk = (const float*)d_in[4];
  const float* bk = (const float*)d_in[5];
  const float* Wv = (const float*)d_in[6];
  const float* bv = (const float*)d_in[7];
  const float* Wo = (const float*)d_in[8];
  const float* bo = (const float*)d_in[9];

  char* ws = (char*)d_ws;
  u16* Xb  = (u16*)(ws);                       // 8 MB
  u16* Yb  = (u16*)(ws + (size_t)(8  << 20));  // 8 MB
  u16* Wb  = (u16*)(ws + (size_t)(16 << 20));  // 4 x 0.5 MB
  u16* Qb  = (u16*)(ws + (size_t)(18 << 20));  // 8 MB [B][H][N][64]
  u16* Kb  = (u16*)(ws + (size_t)(26 << 20));  // 8 MB [B][H][N][64]
  u16* Vtb = (u16*)(ws + (size_t)(34 << 20));  // 8 MB [B][H][64][N]
  u16* Ob  = (u16*)(ws + (size_t)(42 << 20));  // 8 MB [B][N][512]

  k_convall<<<4608, 256, 0, stream>>>(X, Y, Wq, Wk, Wv, Wo, Xb, Yb, Wb);

  k_gemm_qkv<<<dim3(8, 64, 3), 256, 0, stream>>>(Xb, Yb, Wb, bq, bk, bv, Qb, Kb, Vtb);

  k_attn<<<256, 1024, 0, stream>>>(Qb, Kb, Vtb, Ob);

  k_gemm_out<<<dim3(8, 64), 256, 0, stream>>>(Ob, Wb + 3 * 262144, bo, (float*)d_out);
}

// Round 12
// 583.191 us; speedup vs baseline: 1.1349x; 1.1349x over previous
//
#include <hip/hip_runtime.h>
#include <hip/hip_bf16.h>

typedef unsigned short u16;
typedef __attribute__((ext_vector_type(4))) float f32x4;
typedef __attribute__((ext_vector_type(16))) float f32x16;
typedef __attribute__((ext_vector_type(8))) short bf16x8;
typedef __attribute__((ext_vector_type(4))) int i32x4;
typedef __attribute__((ext_vector_type(4))) unsigned short u16x4;

#define DEVI static __device__ __forceinline__

DEVI u16 f2bf(float f) {
  __hip_bfloat16 h = __float2bfloat16(f);
  return *reinterpret_cast<u16*>(&h);
}
DEVI float bf2f(u16 u) {
  unsigned int x = ((unsigned int)u) << 16;
  return __uint_as_float(x);
}
DEVI float exp2a(float x) {
  float r;
  asm("v_exp_f32 %0, %1" : "=v"(r) : "v"(x));
  return r;
}
DEVI int cvtpk(float lo, float hi) {
  int r;
  asm("v_cvt_pk_bf16_f32 %0, %1, %2" : "=v"(r) : "v"(lo), "v"(hi));
  return r;
}
DEVI f32x16 mfma32(bf16x8 a, bf16x8 b, f32x16 c) {
  return __builtin_amdgcn_mfma_f32_32x32x16_bf16(a, b, c, 0, 0, 0);
}
DEVI float xhalf_sum(float x) {
  float a = x, b;
  asm volatile("v_mov_b32 %0, %1" : "=v"(b) : "v"(x));
  asm volatile("v_permlane32_swap_b32 %0, %1" : "+v"(a), "+v"(b));
  return a + b;
}

DEVI void gload_lds16(const void* g, void* l) {
  __builtin_amdgcn_global_load_lds(
      (const __attribute__((address_space(1))) unsigned int*)g,
      (__attribute__((address_space(3))) unsigned int*)l, 16, 0, 0);
}

#define BAR() __builtin_amdgcn_s_barrier()
#define WAITV0() asm volatile("s_waitcnt vmcnt(0)" ::: "memory")
#define WAITV4() asm volatile("s_waitcnt vmcnt(4)" ::: "memory")

// ---------------- fused f32 -> bf16 conversion (X, Y, 4 weights) ----------------
__global__ __launch_bounds__(256) void k_convall(
    const float* __restrict__ X, const float* __restrict__ Y,
    const float* __restrict__ Wq, const float* __restrict__ Wk,
    const float* __restrict__ Wv, const float* __restrict__ Wo,
    u16* __restrict__ Xb, u16* __restrict__ Yb, u16* __restrict__ Wb) {
  long i = ((long)blockIdx.x * 256 + threadIdx.x) * 8;
  const float* s;
  u16* d;
  long off;
  if (i < 4194304) {
    s = X; d = Xb; off = i;
  } else if (i < 8388608) {
    s = Y; d = Yb; off = i - 4194304;
  } else {
    long w = (i - 8388608) >> 18;
    off = (i - 8388608) & 262143;
    s = w == 0 ? Wq : w == 1 ? Wk : w == 2 ? Wv : Wo;
    d = Wb + w * 262144;
  }
  f32x4 a = *(const f32x4*)(s + off);
  f32x4 b = *(const f32x4*)(s + off + 4);
  bf16x8 v;
#pragma unroll
  for (int j = 0; j < 4; ++j) {
    v[j]     = (short)f2bf(a[j]);
    v[4 + j] = (short)f2bf(b[j]);
  }
  *(bf16x8*)(d + off) = v;
}

// ---------------- GEMM core: BM=128 BN=64 BK=64, 4 waves, 2-phase prefetch ------
struct GemmAcc { f32x4 acc[4][2]; };

DEVI void gemm_body(const u16* __restrict__ A, const u16* __restrict__ Bw,
                    int m0, int n0, char* sm, GemmAcc& G) {
  const int tid = threadIdx.x;
  const int wid = tid >> 6, lane = tid & 63;
  const int g = lane >> 4, li = lane & 15;
  const int wr = wid >> 1, wc = wid & 1;

  int arow[4], acol[4];
#pragma unroll
  for (int i = 0; i < 4; ++i) {
    int P0 = ((i * 4 + wid) << 10) + lane * 16;
    int L0 = P0 ^ (((P0 >> 7) & 7) << 4);
    arow[i] = L0 >> 7;
    acol[i] = L0 & 127;
  }

#pragma unroll
  for (int mr = 0; mr < 4; ++mr)
#pragma unroll
    for (int nr = 0; nr < 2; ++nr) G.acc[mr][nr] = (f32x4){0.f, 0.f, 0.f, 0.f};

  auto stage = [&](int kt, int half) {
    char* As = sm + half * 24576;
    char* Bs = As + 16384;
    const int k0b = kt * 128;
#pragma unroll
    for (int i = 0; i < 4; ++i)
      gload_lds16((const char*)A + (size_t)(m0 + arow[i]) * 1024 + k0b + acol[i],
                  As + ((i * 4 + wid) << 10));
#pragma unroll
    for (int i = 0; i < 2; ++i)
      gload_lds16((const char*)Bw + (size_t)(n0 + arow[i]) * 1024 + k0b + acol[i],
                  Bs + ((i * 4 + wid) << 10));
  };

  stage(0, 0);
#pragma unroll 1
  for (int kt = 0; kt < 8; ++kt) {
    const int half = kt & 1;
    if (kt < 7) {
      stage(kt + 1, half ^ 1);
      asm volatile("s_waitcnt vmcnt(6)" ::: "memory");
    } else {
      asm volatile("s_waitcnt vmcnt(0)" ::: "memory");
    }
    BAR();
    const char* As = sm + half * 24576;
    const char* Bs = As + 16384;
#pragma unroll
    for (int ks = 0; ks < 2; ++ks) {
      bf16x8 af[4], bfr[2];
#pragma unroll
      for (int mr = 0; mr < 4; ++mr) {
        int row = wr * 64 + mr * 16 + li;
        int L = row * 128 + ks * 64 + g * 16;
        int P = L ^ ((row & 7) << 4);
        af[mr] = *(const bf16x8*)(As + P);
      }
#pragma unroll
      for (int nr = 0; nr < 2; ++nr) {
        int row = wc * 32 + nr * 16 + li;
        int L = row * 128 + ks * 64 + g * 16;
        int P = L ^ ((row & 7) << 4);
        bfr[nr] = *(const bf16x8*)(Bs + P);
      }
#pragma unroll
      for (int mr = 0; mr < 4; ++mr)
#pragma unroll
        for (int nr = 0; nr < 2; ++nr)
          G.acc[mr][nr] = __builtin_amdgcn_mfma_f32_16x16x32_bf16(
              af[mr], bfr[nr], G.acc[mr][nr], 0, 0, 0);
    }
    BAR();
  }
}

// Fused QKV: z=0 -> Q [B][H][N][64], z=1 -> K same,
// z=2 -> V^T DIRECT: C = Wv @ Y^T -> coalesced [B][H][64][N] writes.
__global__ __launch_bounds__(256) void k_gemm_qkv(
    const u16* __restrict__ Xb, const u16* __restrict__ Yb,
    const u16* __restrict__ Wall, const float* __restrict__ bq,
    const float* __restrict__ bk, const float* __restrict__ bv,
    u16* __restrict__ Qb, u16* __restrict__ Kb, u16* __restrict__ Vtb) {
  __shared__ __align__(16) char sm[49152];
  const int z = blockIdx.z;
  int lin = blockIdx.x + 8 * blockIdx.y;
  int xcd = lin & 7, slot = lin >> 3;

  const u16 *Ag, *Bg;
  int m0, n0;
  if (z == 2) {
    Ag = Wall + 2 * 262144;  // Wv
    Bg = Yb;
    m0 = (slot >> 4) * 128;
    n0 = (xcd * 16 + (slot & 15)) * 64;
  } else {
    Ag = z ? Yb : Xb;
    Bg = Wall + (size_t)z * 262144;
    m0 = (xcd * 8 + (slot >> 3)) * 128;
    n0 = (slot & 7) * 64;
  }

  GemmAcc G;
  gemm_body(Ag, Bg, m0, n0, sm, G);

  const int tid = threadIdx.x;
  const int wid = tid >> 6, lane = tid & 63;
  const int g = lane >> 4, li = lane & 15;
  const int wr = wid >> 1, wc = wid & 1;

  if (z <= 1) {
    u16* Cout = z ? Kb : Qb;
    const float* bias = z ? bk : bq;
#pragma unroll
    for (int nr = 0; nr < 2; ++nr) {
      int col = n0 + wc * 32 + nr * 16 + li;
      float bvv = bias[col];
#pragma unroll
      for (int mr = 0; mr < 4; ++mr) {
#pragma unroll
        for (int j = 0; j < 4; ++j) {
          int row = m0 + wr * 64 + mr * 16 + g * 4 + j;
          float v = G.acc[mr][nr][j] + bvv;
          int b = row >> 11, nn = row & 2047, h = col >> 6, dd = col & 63;
          Cout[(((size_t)(b * 8 + h) << 11) + nn) * 64 + dd] = f2bf(v);
        }
      }
    }
  } else {
#pragma unroll
    for (int mr = 0; mr < 4; ++mr) {
#pragma unroll
      for (int j = 0; j < 4; ++j) {
        int row = m0 + wr * 64 + mr * 16 + g * 4 + j;
        float bvv = bv[row];
        int hh = row >> 6, dd = row & 63;
#pragma unroll
        for (int nr = 0; nr < 2; ++nr) {
          int col = n0 + wc * 32 + nr * 16 + li;
          int b = col >> 11, nn = col & 2047;
          Vtb[(((size_t)(b * 8 + hh) * 64) + dd) * 2048 + nn] =
              f2bf(G.acc[mr][nr][j] + bvv);
        }
      }
    }
  }
}

// Final projection: f32 row-major output [M][512]
__global__ __launch_bounds__(256) void k_gemm_out(const u16* __restrict__ A,
                                                  const u16* __restrict__ Bw,
                                                  const float* __restrict__ bias,
                                                  float* __restrict__ Cout) {
  __shared__ __align__(16) char sm[49152];
  int lin = blockIdx.x + 8 * blockIdx.y;
  int xcd = lin & 7, slot = lin >> 3;
  int by = xcd * 8 + (slot >> 3), bx = slot & 7;
  const int m0 = by * 128, n0 = bx * 64;

  GemmAcc G;
  gemm_body(A, Bw, m0, n0, sm, G);

  const int tid = threadIdx.x;
  const int wid = tid >> 6, lane = tid & 63;
  const int g = lane >> 4, li = lane & 15;
  const int wr = wid >> 1, wc = wid & 1;
#pragma unroll
  for (int nr = 0; nr < 2; ++nr) {
    int col = n0 + wc * 32 + nr * 16 + li;
    float bvv = bias[col];
#pragma unroll
    for (int mr = 0; mr < 4; ++mr) {
#pragma unroll
      for (int j = 0; j < 4; ++j) {
        int row = m0 + wr * 64 + mr * 16 + g * 4 + j;
        Cout[(size_t)row * 512 + col] = G.acc[mr][nr][j] + bvv;
      }
    }
  }
}

// ---------------- flash attention: q=64/wave, kv-split-4, 16 waves, LDS-staged V ----
// Q,K: [B*H][2048][64] bf16; Vt: [B*H][64][2048] bf16; Ob: [B][2048][512] bf16
// 256 blocks (32 bh x 8 qtiles of 256 rows); 16 waves = 4 KV groups x 4 q-waves.
// Group g owns kv quarter (8 tiles of 64); ring (32KB): buf{0,1} x {K 8K, V 8K}.
// launch_bounds(1024,1): second arg = min BLOCKS/CU (CUDA semantics, established
// r7-r11): 1 blk x 16 waves = 4 waves/EU -> VGPR cap 128 >= ~124 needed, no spill.
DEVI void attn_phase(const char* L, int kb, int vb, const int* v4, int sv0, int sv1,
                     const bf16x8* qfA, const bf16x8* qfB,
                     f32x16& oA0, f32x16& oA1, f32x16& oB0, f32x16& oB1,
                     float& lsumA, float& lsumB) {
  const f32x16 Z = {};
  f32x16 sA, sB;
  bf16x8 kf;
  kf = *(const bf16x8*)(L + kb + v4[0]);
  sA = mfma32(kf, qfA[0], Z);  sB = mfma32(kf, qfB[0], Z);
  kf = *(const bf16x8*)(L + kb + v4[1]);
  sA = mfma32(kf, qfA[1], sA); sB = mfma32(kf, qfB[1], sB);
  kf = *(const bf16x8*)(L + kb + v4[2]);
  sA = mfma32(kf, qfA[2], sA); sB = mfma32(kf, qfB[2], sB);
  kf = *(const bf16x8*)(L + kb + v4[3]);
  sA = mfma32(kf, qfA[3], sA); sB = mfma32(kf, qfB[3], sB);

  // V reads issued early: latency hides under the exp block
  bf16x8 va0l = *(const bf16x8*)(L + vb + v4[sv0]);
  bf16x8 va0h = *(const bf16x8*)(L + vb + 4096 + v4[sv0]);
  bf16x8 va1l = *(const bf16x8*)(L + vb + v4[sv1]);
  bf16x8 va1h = *(const bf16x8*)(L + vb + 4096 + v4[sv1]);

  // P = 2^S (Q pre-scaled); row-sums
#pragma unroll
  for (int i = 0; i < 16; ++i) sA[i] = exp2a(sA[i]);
#pragma unroll
  for (int i = 0; i < 16; ++i) sB[i] = exp2a(sB[i]);
  float tA[4], tB[4];
#pragma unroll
  for (int i = 0; i < 4; ++i) {
    tA[i] = (sA[4 * i] + sA[4 * i + 1]) + (sA[4 * i + 2] + sA[4 * i + 3]);
    tB[i] = (sB[4 * i] + sB[4 * i + 1]) + (sB[4 * i + 2] + sB[4 * i + 3]);
  }
  lsumA += (tA[0] + tA[1]) + (tA[2] + tA[3]);
  lsumB += (tB[0] + tB[1]) + (tB[2] + tB[3]);

  // pack P slices: kt=0 -> kv slice sv0, kt=1 -> kv slice sv1
  bf16x8 pbA[2], pbB[2];
#pragma unroll
  for (int kt = 0; kt < 2; ++kt) {
    const int base = kt * 8;
    int a0 = cvtpk(sA[base + 0], sA[base + 1]);
    int a1 = cvtpk(sA[base + 2], sA[base + 3]);
    int b0 = cvtpk(sA[base + 4], sA[base + 5]);
    int b1 = cvtpk(sA[base + 6], sA[base + 7]);
    asm volatile("v_permlane32_swap_b32 %0, %1" : "+v"(a0), "+v"(b0));
    asm volatile("v_permlane32_swap_b32 %0, %1" : "+v"(a1), "+v"(b1));
    i32x4 pi = {a0, a1, b0, b1};
    pbA[kt] = __builtin_bit_cast(bf16x8, pi);
    int c0 = cvtpk(sB[base + 0], sB[base + 1]);
    int c1 = cvtpk(sB[base + 2], sB[base + 3]);
    int d0 = cvtpk(sB[base + 4], sB[base + 5]);
    int d1 = cvtpk(sB[base + 6], sB[base + 7]);
    asm volatile("v_permlane32_swap_b32 %0, %1" : "+v"(c0), "+v"(d0));
    asm volatile("v_permlane32_swap_b32 %0, %1" : "+v"(c1), "+v"(d1));
    i32x4 qi = {c0, c1, d0, d1};
    pbB[kt] = __builtin_bit_cast(bf16x8, qi);
  }

  // PV: each va feeds both q-halves
  oA0 = mfma32(va0l, pbA[0], oA0);
  oB0 = mfma32(va0l, pbB[0], oB0);
  oA1 = mfma32(va0h, pbA[0], oA1);
  oB1 = mfma32(va0h, pbB[0], oB1);
  oA0 = mfma32(va1l, pbA[1], oA0);
  oB0 = mfma32(va1l, pbB[1], oB0);
  oA1 = mfma32(va1h, pbA[1], oA1);
  oB1 = mfma32(va1h, pbB[1], oB1);
}

__global__ __launch_bounds__(1024, 1) void k_attn(const u16* __restrict__ Qb,
                                                  const u16* __restrict__ Kb,
                                                  const u16* __restrict__ Vt,
                                                  u16* __restrict__ Ob) {
  __shared__ __align__(16) char lds[131072];  // 4 groups x 32KB rings; merge reuses
  const int tid = threadIdx.x, wid = tid >> 6, lane = tid & 63;
  const int li = lane & 31, h = lane >> 5;
  const int grp = wid >> 2, w4 = wid & 3;

  const int lin = blockIdx.x;
  const int xcd = lin & 7, slot = lin >> 3;       // slot 0..31
  const int bh = xcd * 4 + (slot >> 3);
  const int qt = slot & 7;                        // 8 q-tiles of 256 rows
  const int start = (slot * 3) & 7;

  const u16* Qh = Qb + ((size_t)bh << 11) * 64;
  const char* Khb = (const char*)(Kb + ((size_t)bh << 11) * 64);
  const char* Vhb = (const char*)(Vt + (size_t)bh * 64 * 2048);

  int v4[4];
  {
    const int swz = (li & 7) << 4;
#pragma unroll
    for (int s = 0; s < 4; ++s) v4[s] = li * 128 + ((s * 32 + h * 16) ^ swz);
  }

  const int qA = qt * 256 + w4 * 64 + li;
  const int qB = qA + 32;
  const float C2 = 0.18033688f;  // 0.125 * log2(e)
  bf16x8 qfA[4], qfB[4];
#pragma unroll
  for (int k4 = 0; k4 < 4; ++k4) {
    bf16x8 fA = *(const bf16x8*)(Qh + (size_t)qA * 64 + k4 * 16 + h * 8);
    bf16x8 fB = *(const bf16x8*)(Qh + (size_t)qB * 64 + k4 * 16 + h * 8);
    bf16x8 rA, rB;
#pragma unroll
    for (int e = 0; e < 4; ++e) {
      int pA = cvtpk(bf2f((u16)fA[2 * e]) * C2, bf2f((u16)fA[2 * e + 1]) * C2);
      rA[2 * e]     = (short)(pA & 0xffff);
      rA[2 * e + 1] = (short)((unsigned)pA >> 16);
      int pB = cvtpk(bf2f((u16)fB[2 * e]) * C2, bf2f((u16)fB[2 * e + 1]) * C2);
      rB[2 * e]     = (short)(pB & 0xffff);
      rB[2 * e + 1] = (short)((unsigned)pB >> 16);
    }
    qfA[k4] = rA;
    qfB[k4] = rB;
  }

  // staging: group's 4 waves cover K tile (8KB) + V tile (8KB); 2KB each per wave
  char* gb = lds + grp * 32768;
  const char* Lg = gb;
  int ksrc[2], vsrc[2];
#pragma unroll
  for (int j = 0; j < 2; ++j) {
    int P0 = w4 * 2048 + j * 1024 + lane * 16;
    int L0 = P0 ^ (((P0 >> 7) & 7) << 4);
    ksrc[j] = L0;
    vsrc[j] = (L0 >> 7) * 4096 + (L0 & 127);
  }

  auto T = [&](int n) { return grp * 8 + ((start + n) & 7); };
  auto stage = [&](int tt, int bb) {
#pragma unroll
    for (int j = 0; j < 2; ++j)
      gload_lds16(Khb + (size_t)tt * 8192 + ksrc[j],
                  gb + bb + w4 * 2048 + j * 1024);
#pragma unroll
    for (int j = 0; j < 2; ++j)
      gload_lds16(Vhb + (size_t)tt * 128 + vsrc[j],
                  gb + bb + 8192 + w4 * 2048 + j * 1024);
  };

  f32x16 oA0 = {}, oA1 = {}, oB0 = {}, oB1 = {};
  float lsumA = 0.f, lsumB = 0.f;

  stage(T(0), 0);
  stage(T(1), 16384);
  WAITV4();  // tile 0 landed
  BAR();

#pragma unroll 1
  for (int it = 0; it < 6; ++it) {
    const int cur = (it & 1) * 16384;
    attn_phase(Lg, cur, cur + 8192, v4, 0, 1, qfA, qfB, oA0, oA1, oB0, oB1,
               lsumA, lsumB);
    attn_phase(Lg, cur + 4096, cur + 8192, v4, 2, 3, qfA, qfB, oA0, oA1, oB0, oB1,
               lsumA, lsumB);
    BAR();
    stage(T(it + 2), cur);
    WAITV4();
    BAR();
  }
  // tile 6
  attn_phase(Lg, 0, 8192, v4, 0, 1, qfA, qfB, oA0, oA1, oB0, oB1, lsumA, lsumB);
  attn_phase(Lg, 4096, 8192, v4, 2, 3, qfA, qfB, oA0, oA1, oB0, oB1, lsumA, lsumB);
  WAITV0();
  BAR();
  // tile 7
  attn_phase(Lg, 16384, 24576, v4, 0, 1, qfA, qfB, oA0, oA1, oB0, oB1, lsumA, lsumB);
  attn_phase(Lg, 20480, 24576, v4, 2, 3, qfA, qfB, oA0, oA1, oB0, oB1, lsumA, lsumB);

  // ---- merge the 4 KV quarters through LDS (common implicit max -> plain adds) ----
  __syncthreads();
  if (grp == 1 || grp == 2) {
    char* dst = lds + (grp - 1) * 65536 + w4 * 16384;
#pragma unroll
    for (int j = 0; j < 16; ++j) {
      const f32x16& o = (j < 4) ? oA0 : (j < 8) ? oA1 : (j < 12) ? oB0 : oB1;
      const int s2 = (j & 3) * 4;
      f32x4 c = {o[s2 + 0], o[s2 + 1], o[s2 + 2], o[s2 + 3]};
      *(f32x4*)(dst + j * 1024 + lane * 16) = c;
    }
  }
  __syncthreads();
  if (grp == 0) {
#pragma unroll
    for (int half = 0; half < 2; ++half) {
      const char* src = lds + half * 65536 + w4 * 16384;
#pragma unroll
      for (int j = 0; j < 16; ++j) {
        f32x4 c = *(const f32x4*)(src + j * 1024 + lane * 16);
        f32x16& o = (j < 4) ? oA0 : (j < 8) ? oA1 : (j < 12) ? oB0 : oB1;
        const int s2 = (j & 3) * 4;
        o[s2 + 0] += c[0]; o[s2 + 1] += c[1]; o[s2 + 2] += c[2]; o[s2 + 3] += c[3];
      }
    }
  }
  __syncthreads();
  if (grp == 3) {
    char* dst = lds + w4 * 16384;
#pragma unroll
    for (int j = 0; j < 16; ++j) {
      const f32x16& o = (j < 4) ? oA0 : (j < 8) ? oA1 : (j < 12) ? oB0 : oB1;
      const int s2 = (j & 3) * 4;
      f32x4 c = {o[s2 + 0], o[s2 + 1], o[s2 + 2], o[s2 + 3]};
      *(f32x4*)(dst + j * 1024 + lane * 16) = c;
    }
  }
  __syncthreads();
  if (grp == 0) {
    const char* src = lds + w4 * 16384;
#pragma unroll
    for (int j = 0; j < 16; ++j) {
      f32x4 c = *(const f32x4*)(src + j * 1024 + lane * 16);
      f32x16& o = (j < 4) ? oA0 : (j < 8) ? oA1 : (j < 12) ? oB0 : oB1;
      const int s2 = (j & 3) * 4;
      o[s2 + 0] += c[0]; o[s2 + 1] += c[1]; o[s2 + 2] += c[2]; o[s2 + 3] += c[3];
    }
  }
  __syncthreads();
  if (grp != 0) {
    float* dst = (float*)(lds + (grp - 1) * 2048) + w4 * 128 + lane * 2;
    dst[0] = lsumA;
    dst[1] = lsumB;
  }
  __syncthreads();
  if (grp == 0) {
#pragma unroll
    for (int g2 = 1; g2 < 4; ++g2) {
      const float* src = (const float*)(lds + (g2 - 1) * 2048) + w4 * 128 + lane * 2;
      lsumA += src[0];
      lsumB += src[1];
    }
    const float invA = 1.0f / xhalf_sum(lsumA);
    const float invB = 1.0f / xhalf_sum(lsumB);

    const int b = bh >> 3, head = bh & 7;
#pragma unroll
    for (int half = 0; half < 2; ++half) {
      const int q = half ? qB : qA;
      const float inv = half ? invB : invA;
      u16* orow = Ob + ((size_t)(b * 2048 + q)) * 512 + head * 64;
      const u16* qrow = Qh + (size_t)q * 64;
#pragma unroll
      for (int dt = 0; dt < 2; ++dt) {
        const f32x16& o = half ? (dt ? oB1 : oB0) : (dt ? oA1 : oA0);
#pragma unroll
        for (int s2 = 0; s2 < 4; ++s2) {
          int d0 = dt * 32 + s2 * 8 + h * 4;
          u16x4 qv = *(const u16x4*)(qrow + d0);
          u16x4 w;
#pragma unroll
          for (int j = 0; j < 4; ++j)
            w[j] = f2bf(fmaf(o[s2 * 4 + j], inv, bf2f(qv[j])));
          *(u16x4*)(orow + d0) = w;
        }
      }
    }
  }
}

// ---------------- launch ----------------
extern "C" void kernel_launch(void* const* d_in, const int* in_sizes, int n_in,
                              void* d_out, int out_size, void* d_ws, size_t ws_size,
                              hipStream_t stream) {
  const float* X  = (const float*)d_in[0];
  const float* Y  = (const float*)d_in[1];
  const float* Wq = (const float*)d_in[2];
  const float* bq = (const float*)d_in[3];
  const float* Wk = (const float*)d_in[4];
  const float* bk = (const float*)d_in[5];
  const float* Wv = (const float*)d_in[6];
  const float* bv = (const float*)d_in[7];
  const float* Wo = (const float*)d_in[8];
  const float* bo = (const float*)d_in[9];

  char* ws = (char*)d_ws;
  u16* Xb  = (u16*)(ws);                       // 8 MB
  u16* Yb  = (u16*)(ws + (size_t)(8  << 20));  // 8 MB
  u16* Wb  = (u16*)(ws + (size_t)(16 << 20));  // 4 x 0.5 MB
  u16* Qb  = (u16*)(ws + (size_t)(18 << 20));  // 8 MB [B][H][N][64]
  u16* Kb  = (u16*)(ws + (size_t)(26 << 20));  // 8 MB [B][H][N][64]
  u16* Vtb = (u16*)(ws + (size_t)(34 << 20));  // 8 MB [B][H][64][N]
  u16* Ob  = (u16*)(ws + (size_t)(42 << 20));  // 8 MB [B][N][512]

  k_convall<<<4608, 256, 0, stream>>>(X, Y, Wq, Wk, Wv, Wo, Xb, Yb, Wb);

  k_gemm_qkv<<<dim3(8, 64, 3), 256, 0, stream>>>(Xb, Yb, Wb, bq, bk, bv, Qb, Kb, Vtb);

  k_attn<<<256, 1024, 0, stream>>>(Qb, Kb, Vtb, Ob);

  k_gemm_out<<<dim3(8, 64), 256, 0, stream>>>(Ob, Wb + 3 * 262144, bo, (float*)d_out);
}

// Round 13
// 84.642 us; speedup vs baseline: 7.8197x; 6.8901x over previous
//
#include <hip/hip_runtime.h>
#include <hip/hip_bf16.h>

typedef unsigned short u16;
typedef __attribute__((ext_vector_type(4))) float f32x4;
typedef __attribute__((ext_vector_type(16))) float f32x16;
typedef __attribute__((ext_vector_type(8))) short bf16x8;
typedef __attribute__((ext_vector_type(4))) int i32x4;
typedef __attribute__((ext_vector_type(4))) unsigned short u16x4;

#define DEVI static __device__ __forceinline__

DEVI u16 f2bf(float f) {
  __hip_bfloat16 h = __float2bfloat16(f);
  return *reinterpret_cast<u16*>(&h);
}
DEVI float bf2f(u16 u) {
  unsigned int x = ((unsigned int)u) << 16;
  return __uint_as_float(x);
}
DEVI float exp2a(float x) {
  float r;
  asm("v_exp_f32 %0, %1" : "=v"(r) : "v"(x));
  return r;
}
DEVI int cvtpk(float lo, float hi) {
  int r;
  asm("v_cvt_pk_bf16_f32 %0, %1, %2" : "=v"(r) : "v"(lo), "v"(hi));
  return r;
}
DEVI f32x16 mfma32(bf16x8 a, bf16x8 b, f32x16 c) {
  return __builtin_amdgcn_mfma_f32_32x32x16_bf16(a, b, c, 0, 0, 0);
}
DEVI float xhalf_sum(float x) {
  float a = x, b;
  asm volatile("v_mov_b32 %0, %1" : "=v"(b) : "v"(x));
  asm volatile("v_permlane32_swap_b32 %0, %1" : "+v"(a), "+v"(b));
  return a + b;
}

DEVI void gload_lds16(const void* g, void* l) {
  __builtin_amdgcn_global_load_lds(
      (const __attribute__((address_space(1))) unsigned int*)g,
      (__attribute__((address_space(3))) unsigned int*)l, 16, 0, 0);
}

#define BAR() __builtin_amdgcn_s_barrier()
#define WAITV0() asm volatile("s_waitcnt vmcnt(0)" ::: "memory")
#define WAITV4() asm volatile("s_waitcnt vmcnt(4)" ::: "memory")
#define WAITV8() asm volatile("s_waitcnt vmcnt(8)" ::: "memory")

// ---------------- fused f32 -> bf16 conversion (X, Y, 4 weights) ----------------
__global__ __launch_bounds__(256) void k_convall(
    const float* __restrict__ X, const float* __restrict__ Y,
    const float* __restrict__ Wq, const float* __restrict__ Wk,
    const float* __restrict__ Wv, const float* __restrict__ Wo,
    u16* __restrict__ Xb, u16* __restrict__ Yb, u16* __restrict__ Wb) {
  long i = ((long)blockIdx.x * 256 + threadIdx.x) * 8;
  const float* s;
  u16* d;
  long off;
  if (i < 4194304) {
    s = X; d = Xb; off = i;
  } else if (i < 8388608) {
    s = Y; d = Yb; off = i - 4194304;
  } else {
    long w = (i - 8388608) >> 18;
    off = (i - 8388608) & 262143;
    s = w == 0 ? Wq : w == 1 ? Wk : w == 2 ? Wv : Wo;
    d = Wb + w * 262144;
  }
  f32x4 a = *(const f32x4*)(s + off);
  f32x4 b = *(const f32x4*)(s + off + 4);
  bf16x8 v;
#pragma unroll
  for (int j = 0; j < 4; ++j) {
    v[j]     = (short)f2bf(a[j]);
    v[4 + j] = (short)f2bf(b[j]);
  }
  *(bf16x8*)(d + off) = v;
}

// ---------- GEMM core: BM=128 BN=128 BK=64 (m97 structure), 2-phase prefetch ----
// sm: half0 {As 16K, Bs 16K} @0, half1 @32768. Total 64KB.
struct GemmAcc { f32x4 acc[4][4]; };

DEVI void gemm_body(const u16* __restrict__ A, const u16* __restrict__ Bw,
                    int m0, int n0, char* sm, GemmAcc& G) {
  const int tid = threadIdx.x;
  const int wid = tid >> 6, lane = tid & 63;
  const int g = lane >> 4, li = lane & 15;
  const int wr = wid >> 1, wc = wid & 1;

  int arow[4], acol[4];
#pragma unroll
  for (int i = 0; i < 4; ++i) {
    int P0 = ((i * 4 + wid) << 10) + lane * 16;
    int L0 = P0 ^ (((P0 >> 7) & 7) << 4);
    arow[i] = L0 >> 7;
    acol[i] = L0 & 127;
  }

#pragma unroll
  for (int mr = 0; mr < 4; ++mr)
#pragma unroll
    for (int nr = 0; nr < 4; ++nr) G.acc[mr][nr] = (f32x4){0.f, 0.f, 0.f, 0.f};

  auto stage = [&](int kt, int half) {
    char* As = sm + half * 32768;
    char* Bs = As + 16384;
    const int k0b = kt * 128;
#pragma unroll
    for (int i = 0; i < 4; ++i)
      gload_lds16((const char*)A + (size_t)(m0 + arow[i]) * 1024 + k0b + acol[i],
                  As + ((i * 4 + wid) << 10));
#pragma unroll
    for (int i = 0; i < 4; ++i)
      gload_lds16((const char*)Bw + (size_t)(n0 + arow[i]) * 1024 + k0b + acol[i],
                  Bs + ((i * 4 + wid) << 10));
  };

  stage(0, 0);
#pragma unroll 1
  for (int kt = 0; kt < 8; ++kt) {
    const int half = kt & 1;
    if (kt < 7) {
      stage(kt + 1, half ^ 1);
      WAITV8();  // kt's 8 loads done; kt+1's 8 still in flight
    } else {
      WAITV0();
    }
    BAR();
    const char* As = sm + half * 32768;
    const char* Bs = As + 16384;
#pragma unroll
    for (int ks = 0; ks < 2; ++ks) {
      bf16x8 af[4], bfr[4];
#pragma unroll
      for (int mr = 0; mr < 4; ++mr) {
        int row = wr * 64 + mr * 16 + li;
        int L = row * 128 + ks * 64 + g * 16;
        int P = L ^ ((row & 7) << 4);
        af[mr] = *(const bf16x8*)(As + P);
      }
#pragma unroll
      for (int nr = 0; nr < 4; ++nr) {
        int row = wc * 64 + nr * 16 + li;
        int L = row * 128 + ks * 64 + g * 16;
        int P = L ^ ((row & 7) << 4);
        bfr[nr] = *(const bf16x8*)(Bs + P);
      }
#pragma unroll
      for (int mr = 0; mr < 4; ++mr)
#pragma unroll
        for (int nr = 0; nr < 4; ++nr)
          G.acc[mr][nr] = __builtin_amdgcn_mfma_f32_16x16x32_bf16(
              af[mr], bfr[nr], G.acc[mr][nr], 0, 0, 0);
    }
    BAR();
  }
}

// Fused QKV: z=0 -> Q [B][H][N][64], z=1 -> K same,
// z=2 -> V^T DIRECT: C = Wv @ Y^T -> coalesced [B][H][64][N] writes.
__global__ __launch_bounds__(256) void k_gemm_qkv(
    const u16* __restrict__ Xb, const u16* __restrict__ Yb,
    const u16* __restrict__ Wall, const float* __restrict__ bq,
    const float* __restrict__ bk, const float* __restrict__ bv,
    u16* __restrict__ Qb, u16* __restrict__ Kb, u16* __restrict__ Vtb) {
  __shared__ __align__(16) char sm[65536];
  const int z = blockIdx.z;
  int lin = blockIdx.x + 4 * blockIdx.y;  // 256 blocks
  int xcd = lin & 7, slot = lin >> 3;     // slot 0..31

  const u16 *Ag, *Bg;
  int m0, n0;
  if (z == 2) {
    Ag = Wall + 2 * 262144;  // Wv
    Bg = Yb;
    m0 = (slot & 3) * 128;                 // dd blocks: 4
    n0 = (xcd * 8 + (slot >> 2)) * 128;    // nn blocks: 64
  } else {
    Ag = z ? Yb : Xb;
    Bg = Wall + (size_t)z * 262144;
    m0 = (xcd * 8 + (slot >> 2)) * 128;    // m blocks: 64
    n0 = (slot & 3) * 128;                 // n blocks: 4
  }

  GemmAcc G;
  gemm_body(Ag, Bg, m0, n0, sm, G);

  const int tid = threadIdx.x;
  const int wid = tid >> 6, lane = tid & 63;
  const int g = lane >> 4, li = lane & 15;
  const int wr = wid >> 1, wc = wid & 1;

  if (z <= 1) {
    u16* Cout = z ? Kb : Qb;
    const float* bias = z ? bk : bq;
#pragma unroll
    for (int nr = 0; nr < 4; ++nr) {
      int col = n0 + wc * 64 + nr * 16 + li;
      float bvv = bias[col];
#pragma unroll
      for (int mr = 0; mr < 4; ++mr) {
#pragma unroll
        for (int j = 0; j < 4; ++j) {
          int row = m0 + wr * 64 + mr * 16 + g * 4 + j;
          float v = G.acc[mr][nr][j] + bvv;
          int b = row >> 11, nn = row & 2047, h = col >> 6, dd = col & 63;
          Cout[(((size_t)(b * 8 + h) << 11) + nn) * 64 + dd] = f2bf(v);
        }
      }
    }
  } else {
#pragma unroll
    for (int mr = 0; mr < 4; ++mr) {
#pragma unroll
      for (int j = 0; j < 4; ++j) {
        int row = m0 + wr * 64 + mr * 16 + g * 4 + j;  // dd-dim 0..511
        float bvv = bv[row];
        int hh = row >> 6, dd = row & 63;
#pragma unroll
        for (int nr = 0; nr < 4; ++nr) {
          int col = n0 + wc * 64 + nr * 16 + li;       // nn-dim 0..8191
          int b = col >> 11, nn = col & 2047;
          Vtb[(((size_t)(b * 8 + hh) * 64) + dd) * 2048 + nn] =
              f2bf(G.acc[mr][nr][j] + bvv);
        }
      }
    }
  }
}

// Final projection: f32 row-major output [M][512]
__global__ __launch_bounds__(256) void k_gemm_out(const u16* __restrict__ A,
                                                  const u16* __restrict__ Bw,
                                                  const float* __restrict__ bias,
                                                  float* __restrict__ Cout) {
  __shared__ __align__(16) char sm[65536];
  int lin = blockIdx.x + 4 * blockIdx.y;
  int xcd = lin & 7, slot = lin >> 3;
  int by = xcd * 8 + (slot >> 2), bx = slot & 3;
  const int m0 = by * 128, n0 = bx * 128;

  GemmAcc G;
  gemm_body(A, Bw, m0, n0, sm, G);

  const int tid = threadIdx.x;
  const int wid = tid >> 6, lane = tid & 63;
  const int g = lane >> 4, li = lane & 15;
  const int wr = wid >> 1, wc = wid & 1;
#pragma unroll
  for (int nr = 0; nr < 4; ++nr) {
    int col = n0 + wc * 64 + nr * 16 + li;
    float bvv = bias[col];
#pragma unroll
    for (int mr = 0; mr < 4; ++mr) {
#pragma unroll
      for (int j = 0; j < 4; ++j) {
        int row = m0 + wr * 64 + mr * 16 + g * 4 + j;
        Cout[(size_t)row * 512 + col] = G.acc[mr][nr][j] + bvv;
      }
    }
  }
}

// ---------------- flash attention (r7 config, session-best: 44.9 us) ----------------
// q=64/wave, kv-phase-split tiles. 256 blocks (32 bh x 8 qtiles of 256 rows);
// 8 waves = 2 KV groups x 4 q-waves. launch_bounds(512,2) -> VGPR 124, no spill.
DEVI void attn_phase(const char* L, int kb, int vb, const int* v4, int sv0, int sv1,
                     const bf16x8* qfA, const bf16x8* qfB,
                     f32x16& oA0, f32x16& oA1, f32x16& oB0, f32x16& oB1,
                     float& lsumA, float& lsumB) {
  const f32x16 Z = {};
  f32x16 sA, sB;
  bf16x8 kf;
  kf = *(const bf16x8*)(L + kb + v4[0]);
  sA = mfma32(kf, qfA[0], Z);  sB = mfma32(kf, qfB[0], Z);
  kf = *(const bf16x8*)(L + kb + v4[1]);
  sA = mfma32(kf, qfA[1], sA); sB = mfma32(kf, qfB[1], sB);
  kf = *(const bf16x8*)(L + kb + v4[2]);
  sA = mfma32(kf, qfA[2], sA); sB = mfma32(kf, qfB[2], sB);
  kf = *(const bf16x8*)(L + kb + v4[3]);
  sA = mfma32(kf, qfA[3], sA); sB = mfma32(kf, qfB[3], sB);

  // V reads issued early: latency hides under the exp block
  bf16x8 va0l = *(const bf16x8*)(L + vb + v4[sv0]);
  bf16x8 va0h = *(const bf16x8*)(L + vb + 4096 + v4[sv0]);
  bf16x8 va1l = *(const bf16x8*)(L + vb + v4[sv1]);
  bf16x8 va1h = *(const bf16x8*)(L + vb + 4096 + v4[sv1]);

  // P = 2^S (Q pre-scaled); row-sums
#pragma unroll
  for (int i = 0; i < 16; ++i) sA[i] = exp2a(sA[i]);
#pragma unroll
  for (int i = 0; i < 16; ++i) sB[i] = exp2a(sB[i]);
  float tA[4], tB[4];
#pragma unroll
  for (int i = 0; i < 4; ++i) {
    tA[i] = (sA[4 * i] + sA[4 * i + 1]) + (sA[4 * i + 2] + sA[4 * i + 3]);
    tB[i] = (sB[4 * i] + sB[4 * i + 1]) + (sB[4 * i + 2] + sB[4 * i + 3]);
  }
  lsumA += (tA[0] + tA[1]) + (tA[2] + tA[3]);
  lsumB += (tB[0] + tB[1]) + (tB[2] + tB[3]);

  // pack P slices: kt=0 -> kv slice sv0, kt=1 -> kv slice sv1
  bf16x8 pbA[2], pbB[2];
#pragma unroll
  for (int kt = 0; kt < 2; ++kt) {
    const int base = kt * 8;
    int a0 = cvtpk(sA[base + 0], sA[base + 1]);
    int a1 = cvtpk(sA[base + 2], sA[base + 3]);
    int b0 = cvtpk(sA[base + 4], sA[base + 5]);
    int b1 = cvtpk(sA[base + 6], sA[base + 7]);
    asm volatile("v_permlane32_swap_b32 %0, %1" : "+v"(a0), "+v"(b0));
    asm volatile("v_permlane32_swap_b32 %0, %1" : "+v"(a1), "+v"(b1));
    i32x4 pi = {a0, a1, b0, b1};
    pbA[kt] = __builtin_bit_cast(bf16x8, pi);
    int c0 = cvtpk(sB[base + 0], sB[base + 1]);
    int c1 = cvtpk(sB[base + 2], sB[base + 3]);
    int d0 = cvtpk(sB[base + 4], sB[base + 5]);
    int d1 = cvtpk(sB[base + 6], sB[base + 7]);
    asm volatile("v_permlane32_swap_b32 %0, %1" : "+v"(c0), "+v"(d0));
    asm volatile("v_permlane32_swap_b32 %0, %1" : "+v"(c1), "+v"(d1));
    i32x4 qi = {c0, c1, d0, d1};
    pbB[kt] = __builtin_bit_cast(bf16x8, qi);
  }

  // PV: each va feeds both q-halves
  oA0 = mfma32(va0l, pbA[0], oA0);
  oB0 = mfma32(va0l, pbB[0], oB0);
  oA1 = mfma32(va0h, pbA[0], oA1);
  oB1 = mfma32(va0h, pbB[0], oB1);
  oA0 = mfma32(va1l, pbA[1], oA0);
  oB0 = mfma32(va1l, pbB[1], oB0);
  oA1 = mfma32(va1h, pbA[1], oA1);
  oB1 = mfma32(va1h, pbB[1], oB1);
}

__global__ __launch_bounds__(512, 2) void k_attn(const u16* __restrict__ Qb,
                                                 const u16* __restrict__ Kb,
                                                 const u16* __restrict__ Vt,
                                                 u16* __restrict__ Ob) {
  __shared__ __align__(16) char lds[67584];  // 2 groups x 32KB rings; merge: 64K+2K
  const int tid = threadIdx.x, wid = tid >> 6, lane = tid & 63;
  const int li = lane & 31, h = lane >> 5;
  const int grp = wid >> 2, w4 = wid & 3;

  const int lin = blockIdx.x;
  const int xcd = lin & 7, slot = lin >> 3;       // slot 0..31
  const int bh = xcd * 4 + (slot >> 3);
  const int qt = slot & 7;                        // 8 q-tiles of 256 rows
  const int start = (slot * 3) & 15;

  const u16* Qh = Qb + ((size_t)bh << 11) * 64;
  const u16* Kh = Kb + ((size_t)bh << 11) * 64;
  const u16* Vh = Vt + (size_t)bh * 64 * 2048;

  int v4[4];
  {
    const int swz = (li & 7) << 4;
#pragma unroll
    for (int s = 0; s < 4; ++s) v4[s] = li * 128 + ((s * 32 + h * 16) ^ swz);
  }

  const int qA = qt * 256 + w4 * 64 + li;
  const int qB = qA + 32;
  const float C2 = 0.18033688f;  // 0.125 * log2(e)
  bf16x8 qfA[4], qfB[4];
#pragma unroll
  for (int k4 = 0; k4 < 4; ++k4) {
    bf16x8 fA = *(const bf16x8*)(Qh + (size_t)qA * 64 + k4 * 16 + h * 8);
    bf16x8 fB = *(const bf16x8*)(Qh + (size_t)qB * 64 + k4 * 16 + h * 8);
    bf16x8 rA, rB;
#pragma unroll
    for (int e = 0; e < 4; ++e) {
      int pA = cvtpk(bf2f((u16)fA[2 * e]) * C2, bf2f((u16)fA[2 * e + 1]) * C2);
      rA[2 * e]     = (short)(pA & 0xffff);
      rA[2 * e + 1] = (short)((unsigned)pA >> 16);
      int pB = cvtpk(bf2f((u16)fB[2 * e]) * C2, bf2f((u16)fB[2 * e + 1]) * C2);
      rB[2 * e]     = (short)(pB & 0xffff);
      rB[2 * e + 1] = (short)((unsigned)pB >> 16);
    }
    qfA[k4] = rA;
    qfB[k4] = rB;
  }

  // staging: group's 4 waves cover K tile (8KB) + V tile (8KB); 2KB each per wave
  char* gb = lds + grp * 32768;
  const char* Lg = gb;
  int ksrc[2], vsrc[2];
#pragma unroll
  for (int j = 0; j < 2; ++j) {
    int P0 = w4 * 2048 + j * 1024 + lane * 16;
    int L0 = P0 ^ (((P0 >> 7) & 7) << 4);
    ksrc[j] = L0;
    vsrc[j] = (L0 >> 7) * 4096 + (L0 & 127);
  }

  auto T = [&](int n) { return grp * 16 + ((start + n) & 15); };
  auto stage = [&](int tt, int bb) {
#pragma unroll
    for (int j = 0; j < 2; ++j)
      gload_lds16((const char*)Kh + (size_t)tt * 8192 + ksrc[j],
                  gb + bb + w4 * 2048 + j * 1024);
#pragma unroll
    for (int j = 0; j < 2; ++j)
      gload_lds16((const char*)Vh + (size_t)tt * 128 + vsrc[j],
                  gb + bb + 8192 + w4 * 2048 + j * 1024);
  };

  f32x16 oA0 = {}, oA1 = {}, oB0 = {}, oB1 = {};
  float lsumA = 0.f, lsumB = 0.f;

  stage(T(0), 0);
  stage(T(1), 16384);
  WAITV4();
  BAR();

#pragma unroll 1
  for (int it = 0; it < 14; ++it) {
    const int cur = (it & 1) * 16384;
    attn_phase(Lg, cur, cur + 8192, v4, 0, 1, qfA, qfB, oA0, oA1, oB0, oB1,
               lsumA, lsumB);
    attn_phase(Lg, cur + 4096, cur + 8192, v4, 2, 3, qfA, qfB, oA0, oA1, oB0, oB1,
               lsumA, lsumB);
    BAR();
    stage(T(it + 2), cur);
    WAITV4();
    BAR();
  }
  attn_phase(Lg, 0, 8192, v4, 0, 1, qfA, qfB, oA0, oA1, oB0, oB1, lsumA, lsumB);
  attn_phase(Lg, 4096, 8192, v4, 2, 3, qfA, qfB, oA0, oA1, oB0, oB1, lsumA, lsumB);
  WAITV0();
  BAR();
  attn_phase(Lg, 16384, 24576, v4, 0, 1, qfA, qfB, oA0, oA1, oB0, oB1, lsumA, lsumB);
  attn_phase(Lg, 20480, 24576, v4, 2, 3, qfA, qfB, oA0, oA1, oB0, oB1, lsumA, lsumB);

  // ---- merge KV halves (partial o,l add; common implicit max) ----
  __syncthreads();
  if (grp == 1) {
#pragma unroll
    for (int j = 0; j < 16; ++j) {
      const f32x16& o = (j < 4) ? oA0 : (j < 8) ? oA1 : (j < 12) ? oB0 : oB1;
      const int s2 = (j & 3) * 4;
      f32x4 c = {o[s2 + 0], o[s2 + 1], o[s2 + 2], o[s2 + 3]};
      *(f32x4*)(lds + w4 * 16384 + j * 1024 + lane * 16) = c;
    }
    ((float*)(lds + 65536))[w4 * 128 + lane] = lsumA;
    ((float*)(lds + 65536))[w4 * 128 + 64 + lane] = lsumB;
  }
  __syncthreads();
  if (grp == 0) {
#pragma unroll
    for (int j = 0; j < 16; ++j) {
      f32x4 c = *(const f32x4*)(lds + w4 * 16384 + j * 1024 + lane * 16);
      f32x16& o = (j < 4) ? oA0 : (j < 8) ? oA1 : (j < 12) ? oB0 : oB1;
      const int s2 = (j & 3) * 4;
      o[s2 + 0] += c[0]; o[s2 + 1] += c[1]; o[s2 + 2] += c[2]; o[s2 + 3] += c[3];
    }
    lsumA += ((const float*)(lds + 65536))[w4 * 128 + lane];
    lsumB += ((const float*)(lds + 65536))[w4 * 128 + 64 + lane];
    const float invA = 1.0f / xhalf_sum(lsumA);
    const float invB = 1.0f / xhalf_sum(lsumB);

    const int b = bh >> 3, head = bh & 7;
#pragma unroll
    for (int half = 0; half < 2; ++half) {
      const int q = half ? qB : qA;
      const float inv = half ? invB : invA;
      u16* orow = Ob + ((size_t)(b * 2048 + q)) * 512 + head * 64;
      const u16* qrow = Qh + (size_t)q * 64;
#pragma unroll
      for (int dt = 0; dt < 2; ++dt) {
        const f32x16& o = half ? (dt ? oB1 : oB0) : (dt ? oA1 : oA0);
#pragma unroll
        for (int s2 = 0; s2 < 4; ++s2) {
          int d0 = dt * 32 + s2 * 8 + h * 4;
          u16x4 qv = *(const u16x4*)(qrow + d0);
          u16x4 w;
#pragma unroll
          for (int j = 0; j < 4; ++j)
            w[j] = f2bf(fmaf(o[s2 * 4 + j], inv, bf2f(qv[j])));
          *(u16x4*)(orow + d0) = w;
        }
      }
    }
  }
}

// ---------------- launch ----------------
extern "C" void kernel_launch(void* const* d_in, const int* in_sizes, int n_in,
                              void* d_out, int out_size, void* d_ws, size_t ws_size,
                              hipStream_t stream) {
  const float* X  = (const float*)d_in[0];
  const float* Y  = (const float*)d_in[1];
  const float* Wq = (const float*)d_in[2];
  const float* bq = (const float*)d_in[3];
  const float* Wk = (const float*)d_in[4];
  const float* bk = (const float*)d_in[5];
  const float* Wv = (const float*)d_in[6];
  const float* bv = (const float*)d_in[7];
  const float* Wo = (const float*)d_in[8];
  const float* bo = (const float*)d_in[9];

  char* ws = (char*)d_ws;
  u16* Xb  = (u16*)(ws);                       // 8 MB
  u16* Yb  = (u16*)(ws + (size_t)(8  << 20));  // 8 MB
  u16* Wb  = (u16*)(ws + (size_t)(16 << 20));  // 4 x 0.5 MB
  u16* Qb  = (u16*)(ws + (size_t)(18 << 20));  // 8 MB [B][H][N][64]
  u16* Kb  = (u16*)(ws + (size_t)(26 << 20));  // 8 MB [B][H][N][64]
  u16* Vtb = (u16*)(ws + (size_t)(34 << 20));  // 8 MB [B][H][64][N]
  u16* Ob  = (u16*)(ws + (size_t)(42 << 20));  // 8 MB [B][N][512]

  k_convall<<<4608, 256, 0, stream>>>(X, Y, Wq, Wk, Wv, Wo, Xb, Yb, Wb);

  k_gemm_qkv<<<dim3(4, 64, 3), 256, 0, stream>>>(Xb, Yb, Wb, bq, bk, bv, Qb, Kb, Vtb);

  k_attn<<<256, 512, 0, stream>>>(Qb, Kb, Vtb, Ob);

  k_gemm_out<<<dim3(4, 64), 256, 0, stream>>>(Ob, Wb + 3 * 262144, bo, (float*)d_out);
}